// Round 10
// baseline (430.240 us; speedup 1.0000x reference)
//
#include <hip/hip_runtime.h>

// Bidirectional LSTM, B=256, T=1024, V=6, D=64, U=64; out = last-step
// concat(h_f, h_b) @ Wd + bd, shape (B,1).
// Reductions: backward dir = ONE step from h0=0 (Wr_b dead); V=6 -> xproj is
// a 6-entry per-lane register table; mask = 6-bit scalar.
// R6: own-gate activation via transpose-butterfly (348us).
// R7: SMEM per-step token loads -> regression (FETCH grew). Reverted.
// R8: h ds_reads first (310us). BEST.
// R9: v_pk_fma_f32 inline asm -> 325us. pk fp32 is HALF-RATE on gfx950
//     (157.3TF = scalar rate); no issue-rate win, asm hurt scheduling. Reverted.
// R10: evict non-h traffic from the in-loop LDS pipe:
//     (a) tokens byte-packed 4/u32 in LDS; ONE uniform ds_read_b32 per 4
//         steps + SALU bfe unpack (was 1 b32/step/wave);
//     (b) proj selected from 6 per-lane registers by SCALAR token (was 1
//         b32/step/wave) -- R7's good half, without global traffic.
//     In-loop LDS = 4x ds_read_b128 (h) + 0.25 pack read + 1 write.

constexpr int kB = 256;
constexpr int kT = 1024;
constexpr int kV = 6;
constexpr int kD = 64;
constexpr int kU = 64;
constexpr int kG = 256; // 4*U gate columns

#define LOG2E 1.44269504f

template <int CTRL>
__device__ __forceinline__ float dppf(float x) {
    return __int_as_float(
        __builtin_amdgcn_mov_dpp(__float_as_int(x), CTRL, 0xF, 0xF, true));
}
constexpr int kXor1 = 0xB1; // quad_perm(1,0,3,2)
constexpr int kXor2 = 0x4E; // quad_perm(2,3,0,1)
constexpr int kBc0 = 0x00, kBc1 = 0x55, kBc2 = 0xAA, kBc3 = 0xFF;

__device__ __forceinline__ float fast_rcp(float x) { return __builtin_amdgcn_rcpf(x); }
__device__ __forceinline__ float exp2_f(float x)   { return __builtin_amdgcn_exp2f(x); }
__device__ __forceinline__ float sig_f(float z)  { return fast_rcp(1.0f + exp2_f(-LOG2E * z)); }
__device__ __forceinline__ float tanh_f(float z) { return 2.0f * fast_rcp(1.0f + exp2_f(-2.0f * LOG2E * z)) - 1.0f; }

__global__ __launch_bounds__(256, 1) void bilstm_last_kernel(
    const int*   __restrict__ tokens, // (B,T)
    const float* __restrict__ emb,    // (6,64)
    const float* __restrict__ Wk_f,   // (64,256)
    const float* __restrict__ Wr_f,   // (64,256)
    const float* __restrict__ b_f,    // (256)
    const float* __restrict__ Wk_b,   // (64,256)
    const float* __restrict__ b_b,    // (256)
    const float* __restrict__ Wd,     // (128)
    const float* __restrict__ bd,     // (1)
    float*       __restrict__ out)    // (B)
{
    __shared__ float s_emb[kV * kD];
    __shared__ float s_projP[kV * kG];            // PERMUTED xproj_f (setup only)
    __shared__ unsigned s_tokp[256];              // tokens byte-packed, 4/u32
    __shared__ float __align__(16) s_h[2][kU];    // double-buffered hidden
    __shared__ float s_act[kG];                   // backward-step scratch

    const int b   = blockIdx.x;
    const int tid = threadIdx.x;
    const int l   = tid & 63;       // lane in wave
    const int wv  = tid >> 6;       // wave id 0..3
    const int s   = l & 3;          // h-slice AND owned gate (0..3 = i,f,g,o)
    const int k   = l >> 2;         // 0..15
    const int u   = wv * 16 + k;    // unit owned by this quad

    // ---- stage emb + byte-packed tokens ----
    for (int i = tid; i < kV * kD; i += 256) s_emb[i] = emb[i];
    {
        const int4 t4 = ((const int4*)(tokens + b * kT))[tid];
        s_tokp[tid] = (unsigned)t4.x | ((unsigned)t4.y << 8) |
                      ((unsigned)t4.z << 16) | ((unsigned)t4.w << 24);
    }
    if (tid < kU) { s_h[0][tid] = 0.0f; s_h[1][tid] = 0.0f; }
    __syncthreads();

    // ---- 6-bit mask, scalarized: bit v = any(emb[v][:] != 0) ----
    unsigned int mbv = 0;
#pragma unroll
    for (int v = 0; v < kV; ++v) {
        const unsigned long long bb = __ballot(s_emb[v * kD + l] != 0.0f);
        mbv |= (bb != 0ull) ? (1u << v) : 0u;
    }
    const unsigned int smb = __builtin_amdgcn_readfirstlane(mbv);

    const int tokL = (int)((__builtin_amdgcn_readfirstlane(s_tokp[255]) >> 24) & 0xFF);

    // ---- proj table (coalesced global reads per column tid), stored PERMUTED
    // so lane q picks up proj[v][ (q&3)*64 + u(q) ] at s_projP[v*256+q].
    float a0 = b_f[tid], a1 = a0, a2 = a0, a3 = a0, a4 = a0, a5 = a0;
    float accb = b_b[tid];
    for (int d = 0; d < kD; ++d) {
        const float wkf = Wk_f[d * kG + tid];
        const float wkb = Wk_b[d * kG + tid];
        a0 = fmaf(s_emb[0 * kD + d], wkf, a0);
        a1 = fmaf(s_emb[1 * kD + d], wkf, a1);
        a2 = fmaf(s_emb[2 * kD + d], wkf, a2);
        a3 = fmaf(s_emb[3 * kD + d], wkf, a3);
        a4 = fmaf(s_emb[4 * kD + d], wkf, a4);
        a5 = fmaf(s_emb[5 * kD + d], wkf, a5);
        accb = fmaf(s_emb[tokL * kD + d], wkb, accb);
    }
    {   // inverse perm: lane q wanting column 'tid' is q = w0*64 + k0*4 + g0
        const int g0 = tid >> 6, u0 = tid & 63, w0 = u0 >> 4, k0 = u0 & 15;
        const int q = w0 * 64 + k0 * 4 + g0;
        s_projP[0 * kG + q] = a0;
        s_projP[1 * kG + q] = a1;
        s_projP[2 * kG + q] = a2;
        s_projP[3 * kG + q] = a3;
        s_projP[4 * kG + q] = a4;
        s_projP[5 * kG + q] = a5;
    }

    // ---- backward single step: z = xproj_b only (h0=0, c0=0 -> f dead) ----
    float ab;
    if (tid < 128)      ab = sig_f(accb);
    else if (tid < 192) ab = tanh_f(accb);
    else                ab = sig_f(accb);
    s_act[tid] = ab;
    __syncthreads();   // covers s_projP stores + s_act
    float hb_val = 0.0f;
    if (tid < kU) {
        const float cb = s_act[tid] * s_act[2 * kU + tid];
        const float hb = s_act[3 * kU + tid] * tanh_f(cb);
        hb_val = ((smb >> tokL) & 1) ? hb : 0.0f;
    }

    // ---- per-lane proj registers: one per vocab value (own gate column) ----
    const float pr0 = s_projP[0 * kG + tid];
    const float pr1 = s_projP[1 * kG + tid];
    const float pr2 = s_projP[2 * kG + tid];
    const float pr3 = s_projP[3 * kG + tid];
    const float pr4 = s_projP[4 * kG + tid];
    const float pr5 = s_projP[5 * kG + tid];

    // ---- recurrent weights: 16 named float4 (unified VGPR/AGPR file) ----
#define DECLW(g, jb)                                                  \
    float4 wq##g##_##jb;                                              \
    wq##g##_##jb.x = Wr_f[(16 * s + 4 * jb + 0) * kG + (g * 64 + u)]; \
    wq##g##_##jb.y = Wr_f[(16 * s + 4 * jb + 1) * kG + (g * 64 + u)]; \
    wq##g##_##jb.z = Wr_f[(16 * s + 4 * jb + 2) * kG + (g * 64 + u)]; \
    wq##g##_##jb.w = Wr_f[(16 * s + 4 * jb + 3) * kG + (g * 64 + u)];
    DECLW(0,0) DECLW(0,1) DECLW(0,2) DECLW(0,3)
    DECLW(1,0) DECLW(1,1) DECLW(1,2) DECLW(1,3)
    DECLW(2,0) DECLW(2,1) DECLW(2,2) DECLW(2,3)
    DECLW(3,0) DECLW(3,1) DECLW(3,2) DECLW(3,3)
#undef DECLW

    // per-lane activation constants: gate s==2 is tanh, others sigmoid
    const bool  isg    = (s == 2);
    const float aScale = isg ? -2.0f * LOG2E : -LOG2E;
    const float aMul   = isg ? 2.0f : 1.0f;
    const float aAdd   = isg ? -1.0f : 0.0f;

    float c = 0.0f, hreg = 0.0f;
    __syncthreads();   // s_h init + pr reads complete before loop

    // ---- scalar packed-token pipeline: sp0 = steps t..t+3, sp1 = next 4 ----
    unsigned sp0 = __builtin_amdgcn_readfirstlane(s_tokp[0]);
    unsigned sp1 = __builtin_amdgcn_readfirstlane(s_tokp[1]);
    unsigned vpackN = 0;

#define MACQ(g, jb, ch)                                      \
        p##g##ch = fmaf(hv##jb.x, wq##g##_##jb.x, p##g##ch); \
        p##g##ch = fmaf(hv##jb.y, wq##g##_##jb.y, p##g##ch); \
        p##g##ch = fmaf(hv##jb.z, wq##g##_##jb.z, p##g##ch); \
        p##g##ch = fmaf(hv##jb.w, wq##g##_##jb.w, p##g##ch);

#define STEP(RP, WP, STOK, PACKRD)                                            \
    {                                                                         \
        /* h reads FIRST: nothing ahead of them in the in-order LDS queue */  \
        const float4* hp = (const float4*)s_h[RP];                            \
        const float4 hv0 = hp[s * 4 + 0];                                     \
        const float4 hv1 = hp[s * 4 + 1];                                     \
        const float4 hv2 = hp[s * 4 + 2];                                     \
        const float4 hv3 = hp[s * 4 + 3];                                     \
        PACKRD                                                                \
        const int stok = (int)(STOK);                                         \
        const int mskc = (int)((smb >> stok) & 1);                            \
        /* own-gate proj from registers, scalar-token select (off chain) */   \
        const float zp = stok == 0 ? pr0 : stok == 1 ? pr1 :                  \
                         stok == 2 ? pr2 : stok == 3 ? pr3 :                  \
                         stok == 4 ? pr4 : pr5;                               \
        float p0a = 0.f, p1a = 0.f, p2a = 0.f, p3a = 0.f;                     \
        float p0b = 0.f, p1b = 0.f, p2b = 0.f, p3b = 0.f;                     \
        MACQ(0,0,a) MACQ(1,0,a) MACQ(2,0,a) MACQ(3,0,a)                       \
        MACQ(0,1,a) MACQ(1,1,a) MACQ(2,1,a) MACQ(3,1,a)                       \
        MACQ(0,2,b) MACQ(1,2,b) MACQ(2,2,b) MACQ(3,2,b)                       \
        MACQ(0,3,b) MACQ(1,3,b) MACQ(2,3,b) MACQ(3,3,b)                       \
        float p0 = p0a + p0b, p1 = p1a + p1b;                                 \
        float p2 = p2a + p2b, p3 = p3a + p3b;                                 \
        /* round 1: 2-lane sums over xor1 pairs, all gates */                 \
        p0 += dppf<kXor1>(p0); p1 += dppf<kXor1>(p1);                         \
        p2 += dppf<kXor1>(p2); p3 += dppf<kXor1>(p3);                         \
        /* select own pair-gate (xor2 partner has same s&1 -> gate-uniform) */\
        float X = (s & 1) ? p1 : p0;                                          \
        float Y = (s & 1) ? p3 : p2;                                          \
        X += dppf<kXor2>(X); Y += dppf<kXor2>(Y);                             \
        const float z = ((s & 2) ? Y : X) + zp;                               \
        /* one activation per lane (own gate) */                              \
        const float e = exp2_f(z * aScale);                                   \
        const float r = fast_rcp(1.0f + e);                                   \
        const float a = fmaf(r, aMul, aAdd);                                  \
        /* quad broadcasts: gate q lives in lane q of the quad */             \
        const float ai = dppf<kBc0>(a);                                       \
        const float af = dppf<kBc1>(a);                                       \
        const float ag = dppf<kBc2>(a);                                       \
        const float ao = dppf<kBc3>(a);                                       \
        const float cn = fmaf(af, c, ai * ag);                                \
        const float hn = ao * tanh_f(cn);                                     \
        if (mskc) { c = cn; hreg = hn; }   /* uniform branch */               \
        if (s == 0) s_h[WP][u] = hreg;                                        \
        __syncthreads();                                                      \
    }

    for (int t4 = 0; t4 < kT / 4; ++t4) {
        STEP(0, 1, sp0 & 0xFF,
             vpackN = s_tokp[(t4 + 2) & 255];)   // uniform-addr b32, 1 per 4 steps
        STEP(1, 0, (sp0 >> 8) & 0xFF, )
        STEP(0, 1, (sp0 >> 16) & 0xFF, )
        STEP(1, 0, (sp0 >> 24) & 0xFF, )
        sp0 = sp1;
        sp1 = __builtin_amdgcn_readfirstlane(vpackN);
    }
#undef STEP
#undef MACQ

    // final h in s_h[0] (step 1023 reads s_h[1], writes s_h[0])
    if (tid < kU) {
        float v = s_h[0][tid] * Wd[tid] + hb_val * Wd[kU + tid];
#pragma unroll
        for (int off = 32; off > 0; off >>= 1) v += __shfl_down(v, off, 64);
        if (tid == 0) out[b] = v + bd[0];
    }
}

extern "C" void kernel_launch(void* const* d_in, const int* in_sizes, int n_in,
                              void* d_out, int out_size, void* d_ws, size_t ws_size,
                              hipStream_t stream) {
    const int*   tokens = (const int*)d_in[0];
    const float* emb    = (const float*)d_in[1];
    const float* Wk_f   = (const float*)d_in[2];
    const float* Wr_f   = (const float*)d_in[3];
    const float* b_f    = (const float*)d_in[4];
    const float* Wk_b   = (const float*)d_in[5];
    // d_in[6] = Wr_b: unused (backward runs one step from h0=0)
    const float* b_b    = (const float*)d_in[7];
    const float* Wd     = (const float*)d_in[8];
    const float* bd     = (const float*)d_in[9];
    float* out = (float*)d_out;

    bilstm_last_kernel<<<kB, 256, 0, stream>>>(
        tokens, emb, Wk_f, Wr_f, b_f, Wk_b, b_b, Wd, bd, out);
}

// Round 11
// 352.862 us; speedup vs baseline: 1.2193x; 1.2193x over previous
//
#include <hip/hip_runtime.h>

// Bidirectional LSTM, B=256, T=1024, V=6, D=64, U=64; out = last-step
// concat(h_f, h_b) @ Wd + bd, shape (B,1).
// Reductions: backward dir = ONE step from h0=0 (Wr_b dead); V=6 -> xproj is
// a 6x256 table; mask = 6-bit scalar.
// R6: own-gate activation via transpose-butterfly (348us).
// R7: SMEM per-step token loads -> regression. R9: v_pk fp32 is half-rate on
//     gfx950 -> regression. R10: register-select proj + byte-packed tokens ->
//     regression (+107 VALU cyc/step in cndmask trees). All reverted.
// R8: h ds_reads first (310us). BEST baseline for this round.
// R11: R8 + PADDED h layout. Old layout put slices at float offsets
//     {0,64,128,192} -> banks {0,16,0,16}: every ds_read_b128 was a 2-way
//     bank conflict (SQ_LDS_BANK_CONFLICT=36864 = 36 cyc/step). New layout:
//     slice s at float 20*s (pad +4). Banks for line j: {4j,20+4j,8+4j,28+4j}
//     -- conflict-free for all j. Writer: unit u=16w+k -> offset 20w+k.

constexpr int kB = 256;
constexpr int kT = 1024;
constexpr int kV = 6;
constexpr int kD = 64;
constexpr int kU = 64;
constexpr int kG = 256; // 4*U gate columns
constexpr int kHP = 80; // padded h buffer: 4 slices x 20 floats

#define LOG2E 1.44269504f

typedef float v2f __attribute__((ext_vector_type(2)));

template <int CTRL>
__device__ __forceinline__ float dppf(float x) {
    return __int_as_float(
        __builtin_amdgcn_mov_dpp(__float_as_int(x), CTRL, 0xF, 0xF, true));
}
constexpr int kXor1 = 0xB1; // quad_perm(1,0,3,2)
constexpr int kXor2 = 0x4E; // quad_perm(2,3,0,1)
constexpr int kBc0 = 0x00, kBc1 = 0x55, kBc2 = 0xAA, kBc3 = 0xFF;

__device__ __forceinline__ float fast_rcp(float x) { return __builtin_amdgcn_rcpf(x); }
__device__ __forceinline__ float exp2_f(float x)   { return __builtin_amdgcn_exp2f(x); }
__device__ __forceinline__ float sig_f(float z)  { return fast_rcp(1.0f + exp2_f(-LOG2E * z)); }
__device__ __forceinline__ float tanh_f(float z) { return 2.0f * fast_rcp(1.0f + exp2_f(-2.0f * LOG2E * z)) - 1.0f; }

__global__ __launch_bounds__(256, 1) void bilstm_last_kernel(
    const int*   __restrict__ tokens, // (B,T)
    const float* __restrict__ emb,    // (6,64)
    const float* __restrict__ Wk_f,   // (64,256)
    const float* __restrict__ Wr_f,   // (64,256)
    const float* __restrict__ b_f,    // (256)
    const float* __restrict__ Wk_b,   // (64,256)
    const float* __restrict__ b_b,    // (256)
    const float* __restrict__ Wd,     // (128)
    const float* __restrict__ bd,     // (1)
    float*       __restrict__ out)    // (B)
{
    __shared__ float s_emb[kV * kD];
    __shared__ float s_projP[kV * kG];            // PERMUTED xproj_f table
    __shared__ int   s_tok[kT];
    __shared__ float __align__(16) s_h[2][kHP];   // double-buffered PADDED h
    __shared__ float s_act[kG];                   // backward-step scratch

    const int b   = blockIdx.x;
    const int tid = threadIdx.x;
    const int l   = tid & 63;       // lane in wave
    const int wv  = tid >> 6;       // wave id 0..3
    const int s   = l & 3;          // h-slice AND owned gate (0..3 = i,f,g,o)
    const int k   = l >> 2;         // 0..15
    const int u   = wv * 16 + k;    // unit owned by this quad
    const int hw  = 20 * wv + k;    // padded write offset for unit u

    // ---- stage emb + tokens ----
    for (int i = tid; i < kV * kD; i += 256) s_emb[i] = emb[i];
    ((int4*)s_tok)[tid] = ((const int4*)(tokens + b * kT))[tid];
    if (tid < kHP) { s_h[0][tid] = 0.0f; s_h[1][tid] = 0.0f; }
    __syncthreads();

    // ---- 6-bit mask, scalarized: bit v = any(emb[v][:] != 0) ----
    unsigned int mbv = 0;
#pragma unroll
    for (int v = 0; v < kV; ++v) {
        const unsigned long long bb = __ballot(s_emb[v * kD + l] != 0.0f);
        mbv |= (bb != 0ull) ? (1u << v) : 0u;
    }
    const unsigned int smb = __builtin_amdgcn_readfirstlane(mbv);

    const int tokL = s_tok[kT - 1];

    // ---- proj table (coalesced global reads per column tid), stored PERMUTED
    // so lane q of the step loop reads proj[v][ (q&3)*64 + u(q) ] at
    // s_projP[v*256+q].
    float a0 = b_f[tid], a1 = a0, a2 = a0, a3 = a0, a4 = a0, a5 = a0;
    float accb = b_b[tid];
    for (int d = 0; d < kD; ++d) {
        const float wkf = Wk_f[d * kG + tid];
        const float wkb = Wk_b[d * kG + tid];
        a0 = fmaf(s_emb[0 * kD + d], wkf, a0);
        a1 = fmaf(s_emb[1 * kD + d], wkf, a1);
        a2 = fmaf(s_emb[2 * kD + d], wkf, a2);
        a3 = fmaf(s_emb[3 * kD + d], wkf, a3);
        a4 = fmaf(s_emb[4 * kD + d], wkf, a4);
        a5 = fmaf(s_emb[5 * kD + d], wkf, a5);
        accb = fmaf(s_emb[tokL * kD + d], wkb, accb);
    }
    {   // inverse perm: lane q wanting column 'tid' is q = w0*64 + k0*4 + g0
        const int g0 = tid >> 6, u0 = tid & 63, w0 = u0 >> 4, k0 = u0 & 15;
        const int q = w0 * 64 + k0 * 4 + g0;
        s_projP[0 * kG + q] = a0;
        s_projP[1 * kG + q] = a1;
        s_projP[2 * kG + q] = a2;
        s_projP[3 * kG + q] = a3;
        s_projP[4 * kG + q] = a4;
        s_projP[5 * kG + q] = a5;
    }

    // ---- backward single step: z = xproj_b only (h0=0, c0=0 -> f dead) ----
    float ab;
    if (tid < 128)      ab = sig_f(accb);
    else if (tid < 192) ab = tanh_f(accb);
    else                ab = sig_f(accb);
    s_act[tid] = ab;
    __syncthreads();
    float hb_val = 0.0f;
    if (tid < kU) {
        const float cb = s_act[tid] * s_act[2 * kU + tid];
        const float hb = s_act[3 * kU + tid] * tanh_f(cb);
        hb_val = ((smb >> tokL) & 1) ? hb : 0.0f;
    }

    // ---- recurrent weights: 16 named float4 (unified VGPR/AGPR file) ----
#define DECLW(g, jb)                                                  \
    float4 wq##g##_##jb;                                              \
    wq##g##_##jb.x = Wr_f[(16 * s + 4 * jb + 0) * kG + (g * 64 + u)]; \
    wq##g##_##jb.y = Wr_f[(16 * s + 4 * jb + 1) * kG + (g * 64 + u)]; \
    wq##g##_##jb.z = Wr_f[(16 * s + 4 * jb + 2) * kG + (g * 64 + u)]; \
    wq##g##_##jb.w = Wr_f[(16 * s + 4 * jb + 3) * kG + (g * 64 + u)];
    DECLW(0,0) DECLW(0,1) DECLW(0,2) DECLW(0,3)
    DECLW(1,0) DECLW(1,1) DECLW(1,2) DECLW(1,3)
    DECLW(2,0) DECLW(2,1) DECLW(2,2) DECLW(2,3)
    DECLW(3,0) DECLW(3,1) DECLW(3,2) DECLW(3,3)
#undef DECLW

    // per-lane activation constants: gate s==2 is tanh, others sigmoid
    const bool  isg    = (s == 2);
    const float aScale = isg ? -2.0f * LOG2E : -LOG2E;
    const float aMul   = isg ? 2.0f : 1.0f;
    const float aAdd   = isg ? -1.0f : 0.0f;

    float c = 0.0f, hreg = 0.0f;
    __syncthreads();   // projP + s_h init visible

    // ---- scalar token pipeline, depth 2 (through LDS, as in R6/R8) ----
    int stok0 = __builtin_amdgcn_readfirstlane(s_tok[0]);
    float zcur = s_projP[stok0 * kG + tid];   // own-gate proj for this lane
    int   mskc = (smb >> stok0) & 1;          // scalar
    int   stokA = __builtin_amdgcn_readfirstlane(s_tok[1]);

    // 64 MACs: 8 scalar-equivalent chains via v2f elementwise (as in R8)
#define MACQ(g, jb)                                                       \
        pk##g = __builtin_elementwise_fma(                                \
            (v2f){hv##jb.x, hv##jb.y},                                    \
            (v2f){wq##g##_##jb.x, wq##g##_##jb.y}, pk##g);                \
        qk##g = __builtin_elementwise_fma(                                \
            (v2f){hv##jb.z, hv##jb.w},                                    \
            (v2f){wq##g##_##jb.z, wq##g##_##jb.w}, qk##g);

#define STEP(RP, WP, TT)                                                      \
    {                                                                         \
        /* h reads FIRST; padded layout: slice s at float4 index 5*s */       \
        const float4* hp = (const float4*)s_h[RP];                            \
        const float4 hv0 = hp[s * 5 + 0];                                     \
        const float4 hv1 = hp[s * 5 + 1];                                     \
        const float4 hv2 = hp[s * 5 + 2];                                     \
        const float4 hv3 = hp[s * 5 + 3];                                     \
        /* prefetches behind h in the queue; consumed next step */            \
        const int   vtokB = s_tok[((TT) + 2) & (kT - 1)];                     \
        const float znext = s_projP[stokA * kG + tid];                        \
        const int   mskn  = (int)((smb >> stokA) & 1);                        \
        v2f pk0 = {0.f,0.f}, pk1 = {0.f,0.f}, pk2 = {0.f,0.f}, pk3 = {0.f,0.f};\
        v2f qk0 = {0.f,0.f}, qk1 = {0.f,0.f}, qk2 = {0.f,0.f}, qk3 = {0.f,0.f};\
        MACQ(0,0) MACQ(1,0) MACQ(2,0) MACQ(3,0)                               \
        MACQ(0,1) MACQ(1,1) MACQ(2,1) MACQ(3,1)                               \
        MACQ(0,2) MACQ(1,2) MACQ(2,2) MACQ(3,2)                               \
        MACQ(0,3) MACQ(1,3) MACQ(2,3) MACQ(3,3)                               \
        const v2f v0 = pk0 + qk0, v1 = pk1 + qk1;                             \
        const v2f v2 = pk2 + qk2, v3 = pk3 + qk3;                             \
        float p0 = v0.x + v0.y, p1 = v1.x + v1.y;                             \
        float p2 = v2.x + v2.y, p3 = v3.x + v3.y;                             \
        /* round 1: 2-lane sums over xor1 pairs, all gates */                 \
        p0 += dppf<kXor1>(p0); p1 += dppf<kXor1>(p1);                         \
        p2 += dppf<kXor1>(p2); p3 += dppf<kXor1>(p3);                         \
        /* select own pair-gate (xor2 partner has same s&1 -> gate-uniform) */\
        float X = (s & 1) ? p1 : p0;                                          \
        float Y = (s & 1) ? p3 : p2;                                          \
        X += dppf<kXor2>(X); Y += dppf<kXor2>(Y);                             \
        const float z = ((s & 2) ? Y : X) + zcur;                             \
        /* one activation per lane (own gate) */                              \
        const float e = exp2_f(z * aScale);                                   \
        const float r = fast_rcp(1.0f + e);                                   \
        const float a = fmaf(r, aMul, aAdd);                                  \
        /* quad broadcasts: gate q lives in lane q of the quad */             \
        const float ai = dppf<kBc0>(a);                                       \
        const float af = dppf<kBc1>(a);                                       \
        const float ag = dppf<kBc2>(a);                                       \
        const float ao = dppf<kBc3>(a);                                       \
        const float cn = fmaf(af, c, ai * ag);                                \
        const float hn = ao * tanh_f(cn);                                     \
        if (mskc) { c = cn; hreg = hn; }   /* uniform branch */               \
        if (s == 0) s_h[WP][hw] = hreg;    /* padded write: 20*wv + k */      \
        __syncthreads();                                                      \
        zcur = znext; mskc = mskn;                                            \
        stokA = __builtin_amdgcn_readfirstlane(vtokB);                        \
    }

    for (int t = 0; t < kT; t += 2) {
        STEP(0, 1, t)
        STEP(1, 0, t + 1)
    }
#undef STEP
#undef MACQ

    // final h in s_h[0] (step 1023 reads s_h[1], writes s_h[0]); padded index
    if (tid < kU) {
        const float hf = s_h[0][tid + ((tid >> 4) << 2)];  // 20*(u/16)+(u%16)
        float v = hf * Wd[tid] + hb_val * Wd[kU + tid];
#pragma unroll
        for (int off = 32; off > 0; off >>= 1) v += __shfl_down(v, off, 64);
        if (tid == 0) out[b] = v + bd[0];
    }
}

extern "C" void kernel_launch(void* const* d_in, const int* in_sizes, int n_in,
                              void* d_out, int out_size, void* d_ws, size_t ws_size,
                              hipStream_t stream) {
    const int*   tokens = (const int*)d_in[0];
    const float* emb    = (const float*)d_in[1];
    const float* Wk_f   = (const float*)d_in[2];
    const float* Wr_f   = (const float*)d_in[3];
    const float* b_f    = (const float*)d_in[4];
    const float* Wk_b   = (const float*)d_in[5];
    // d_in[6] = Wr_b: unused (backward runs one step from h0=0)
    const float* b_b    = (const float*)d_in[7];
    const float* Wd     = (const float*)d_in[8];
    const float* bd     = (const float*)d_in[9];
    float* out = (float*)d_out;

    bilstm_last_kernel<<<kB, 256, 0, stream>>>(
        tokens, emb, Wk_f, Wr_f, b_f, Wk_b, b_b, Wd, bd, out);
}

// Round 12
// 343.905 us; speedup vs baseline: 1.2510x; 1.0260x over previous
//
#include <hip/hip_runtime.h>

// Bidirectional LSTM, B=256, T=1024, V=6, D=64, U=64; out = last-step
// concat(h_f, h_b) @ Wd + bd, shape (B,1).
// Reductions: backward dir = ONE step from h0=0 (Wr_b dead); V=6 -> xproj is
// a 6x256 table; mask = 6-bit scalar.
// R6: own-gate act via transpose-butterfly (348us). R8: h-reads-first (310us).
// R7/R9/R10: SMEM tokens / pk-fp32 / reg-select proj all regressed. Reverted.
// R11: padded h layout -> conflicts UNCHANGED (37k is benign 2-way counting);
//      ~R8 time. With 4 waves on 4 SIMDs the step = per-wave issue + exposed
//      latency, serial. Lever: shrink issue + h payload.
// R12: f16 arithmetic for the 64-MAC block via v_dot2_f32_f16 (full rate,
//      2 MAC/inst, f32 accumulate): 32 dot2 = 64 cyc issue (was 128).
//      h exchanged as f16: slice = 16 halves = 2x ds_read_b128 (was 4),
//      4 slices span all 32 banks exactly once. c, gates, z, and the
//      lane-resident h (epilogue) stay f32; only Wr and the fed-back h copy
//      are rounded -> est. output err ~1e-4 << 2.37e-3 threshold.

constexpr int kB = 256;
constexpr int kT = 1024;
constexpr int kV = 6;
constexpr int kD = 64;
constexpr int kU = 64;
constexpr int kG = 256; // 4*U gate columns

#define LOG2E 1.44269504f

typedef _Float16 v2h __attribute__((ext_vector_type(2)));

template <int CTRL>
__device__ __forceinline__ float dppf(float x) {
    return __int_as_float(
        __builtin_amdgcn_mov_dpp(__float_as_int(x), CTRL, 0xF, 0xF, true));
}
constexpr int kXor1 = 0xB1; // quad_perm(1,0,3,2)
constexpr int kXor2 = 0x4E; // quad_perm(2,3,0,1)
constexpr int kBc0 = 0x00, kBc1 = 0x55, kBc2 = 0xAA, kBc3 = 0xFF;

__device__ __forceinline__ float fast_rcp(float x) { return __builtin_amdgcn_rcpf(x); }
__device__ __forceinline__ float exp2_f(float x)   { return __builtin_amdgcn_exp2f(x); }
__device__ __forceinline__ float sig_f(float z)  { return fast_rcp(1.0f + exp2_f(-LOG2E * z)); }
__device__ __forceinline__ float tanh_f(float z) { return 2.0f * fast_rcp(1.0f + exp2_f(-2.0f * LOG2E * z)) - 1.0f; }

__device__ __forceinline__ v2h as_v2h(float x) { return __builtin_bit_cast(v2h, x); }

__global__ __launch_bounds__(256, 1) void bilstm_last_kernel(
    const int*   __restrict__ tokens, // (B,T)
    const float* __restrict__ emb,    // (6,64)
    const float* __restrict__ Wk_f,   // (64,256)
    const float* __restrict__ Wr_f,   // (64,256)
    const float* __restrict__ b_f,    // (256)
    const float* __restrict__ Wk_b,   // (64,256)
    const float* __restrict__ b_b,    // (256)
    const float* __restrict__ Wd,     // (128)
    const float* __restrict__ bd,     // (1)
    float*       __restrict__ out)    // (B)
{
    __shared__ float s_emb[kV * kD];
    __shared__ float s_projP[kV * kG];              // PERMUTED xproj_f table
    __shared__ int   s_tok[kT];
    __shared__ _Float16 __align__(16) s_hh[2][kU];  // double-buffered h (f16)
    __shared__ float s_act[kG];                     // scratch (bwd step + epilogue)

    const int b   = blockIdx.x;
    const int tid = threadIdx.x;
    const int l   = tid & 63;       // lane in wave
    const int wv  = tid >> 6;       // wave id 0..3
    const int s   = l & 3;          // h-slice AND owned gate (0..3 = i,f,g,o)
    const int k   = l >> 2;         // 0..15
    const int u   = wv * 16 + k;    // unit owned by this quad

    // ---- stage emb + tokens ----
    for (int i = tid; i < kV * kD; i += 256) s_emb[i] = emb[i];
    ((int4*)s_tok)[tid] = ((const int4*)(tokens + b * kT))[tid];
    if (tid < kU) { s_hh[0][tid] = (_Float16)0.f; s_hh[1][tid] = (_Float16)0.f; }
    __syncthreads();

    // ---- 6-bit mask, scalarized: bit v = any(emb[v][:] != 0) ----
    unsigned int mbv = 0;
#pragma unroll
    for (int v = 0; v < kV; ++v) {
        const unsigned long long bb = __ballot(s_emb[v * kD + l] != 0.0f);
        mbv |= (bb != 0ull) ? (1u << v) : 0u;
    }
    const unsigned int smb = __builtin_amdgcn_readfirstlane(mbv);

    const int tokL = s_tok[kT - 1];

    // ---- proj table (coalesced global reads per column tid), stored PERMUTED
    // so lane q of the step loop reads proj[v][ (q&3)*64 + u(q) ] at
    // s_projP[v*256+q].
    float a0 = b_f[tid], a1 = a0, a2 = a0, a3 = a0, a4 = a0, a5 = a0;
    float accb = b_b[tid];
    for (int d = 0; d < kD; ++d) {
        const float wkf = Wk_f[d * kG + tid];
        const float wkb = Wk_b[d * kG + tid];
        a0 = fmaf(s_emb[0 * kD + d], wkf, a0);
        a1 = fmaf(s_emb[1 * kD + d], wkf, a1);
        a2 = fmaf(s_emb[2 * kD + d], wkf, a2);
        a3 = fmaf(s_emb[3 * kD + d], wkf, a3);
        a4 = fmaf(s_emb[4 * kD + d], wkf, a4);
        a5 = fmaf(s_emb[5 * kD + d], wkf, a5);
        accb = fmaf(s_emb[tokL * kD + d], wkb, accb);
    }
    {   // inverse perm: lane q wanting column 'tid' is q = w0*64 + k0*4 + g0
        const int g0 = tid >> 6, u0 = tid & 63, w0 = u0 >> 4, k0 = u0 & 15;
        const int q = w0 * 64 + k0 * 4 + g0;
        s_projP[0 * kG + q] = a0;
        s_projP[1 * kG + q] = a1;
        s_projP[2 * kG + q] = a2;
        s_projP[3 * kG + q] = a3;
        s_projP[4 * kG + q] = a4;
        s_projP[5 * kG + q] = a5;
    }

    // ---- backward single step: z = xproj_b only (h0=0, c0=0 -> f dead) ----
    float ab;
    if (tid < 128)      ab = sig_f(accb);
    else if (tid < 192) ab = tanh_f(accb);
    else                ab = sig_f(accb);
    s_act[tid] = ab;
    __syncthreads();
    float hb_val = 0.0f;
    if (tid < kU) {
        const float cb = s_act[tid] * s_act[2 * kU + tid];
        const float hb = s_act[3 * kU + tid] * tanh_f(cb);
        hb_val = ((smb >> tokL) & 1) ? hb : 0.0f;
    }

    // ---- recurrent weights: f16 pairs, 8 v2h per gate (32 VGPRs total) ----
#define DECLH(g, p)                                                         \
    v2h wh##g##_##p;                                                        \
    wh##g##_##p.x = (_Float16)Wr_f[(16 * s + 2 * p + 0) * kG + (g * 64 + u)]; \
    wh##g##_##p.y = (_Float16)Wr_f[(16 * s + 2 * p + 1) * kG + (g * 64 + u)];
    DECLH(0,0) DECLH(0,1) DECLH(0,2) DECLH(0,3) DECLH(0,4) DECLH(0,5) DECLH(0,6) DECLH(0,7)
    DECLH(1,0) DECLH(1,1) DECLH(1,2) DECLH(1,3) DECLH(1,4) DECLH(1,5) DECLH(1,6) DECLH(1,7)
    DECLH(2,0) DECLH(2,1) DECLH(2,2) DECLH(2,3) DECLH(2,4) DECLH(2,5) DECLH(2,6) DECLH(2,7)
    DECLH(3,0) DECLH(3,1) DECLH(3,2) DECLH(3,3) DECLH(3,4) DECLH(3,5) DECLH(3,6) DECLH(3,7)
#undef DECLH

    // per-lane activation constants: gate s==2 is tanh, others sigmoid
    const bool  isg    = (s == 2);
    const float aScale = isg ? -2.0f * LOG2E : -LOG2E;
    const float aMul   = isg ? 2.0f : 1.0f;
    const float aAdd   = isg ? -1.0f : 0.0f;

    float c = 0.0f, hreg = 0.0f;
    __syncthreads();   // projP + s_hh init visible

    // ---- scalar token pipeline, depth 2 (through LDS, as in R6/R8) ----
    int stok0 = __builtin_amdgcn_readfirstlane(s_tok[0]);
    float zcur = s_projP[stok0 * kG + tid];   // own-gate proj for this lane
    int   mskc = (smb >> stok0) & 1;          // scalar
    int   stokA = __builtin_amdgcn_readfirstlane(s_tok[1]);

    // per gate: 8 dot2 in 2 chains of depth 4, then 1 add
#define DOTG(g)                                                               \
        float pa##g = __builtin_amdgcn_fdot2(H0, wh##g##_0, 0.0f, false);     \
        float pb##g = __builtin_amdgcn_fdot2(H1, wh##g##_1, 0.0f, false);     \
        pa##g = __builtin_amdgcn_fdot2(H2, wh##g##_2, pa##g, false);          \
        pb##g = __builtin_amdgcn_fdot2(H3, wh##g##_3, pb##g, false);          \
        pa##g = __builtin_amdgcn_fdot2(H4, wh##g##_4, pa##g, false);          \
        pb##g = __builtin_amdgcn_fdot2(H5, wh##g##_5, pb##g, false);          \
        pa##g = __builtin_amdgcn_fdot2(H6, wh##g##_6, pa##g, false);          \
        pb##g = __builtin_amdgcn_fdot2(H7, wh##g##_7, pb##g, false);          \
        float p##g = pa##g + pb##g;

#define STEP(RP, WP, TT)                                                      \
    {                                                                         \
        /* h reads FIRST; slice s = 16 halves = 32B = 2x b128; the 4 slices   \
           cover all 32 banks exactly once -> conflict-free */                \
        const float4* hp = (const float4*)s_hh[RP];                           \
        const float4 hv0 = hp[s * 2 + 0];                                     \
        const float4 hv1 = hp[s * 2 + 1];                                     \
        /* prefetches behind h in the queue; consumed next step */            \
        const int   vtokB = s_tok[((TT) + 2) & (kT - 1)];                     \
        const float znext = s_projP[stokA * kG + tid];                        \
        const int   mskn  = (int)((smb >> stokA) & 1);                        \
        const v2h H0 = as_v2h(hv0.x), H1 = as_v2h(hv0.y);                     \
        const v2h H2 = as_v2h(hv0.z), H3 = as_v2h(hv0.w);                     \
        const v2h H4 = as_v2h(hv1.x), H5 = as_v2h(hv1.y);                     \
        const v2h H6 = as_v2h(hv1.z), H7 = as_v2h(hv1.w);                     \
        DOTG(0) DOTG(1) DOTG(2) DOTG(3)                                       \
        /* round 1: 2-lane sums over xor1 pairs, all gates */                 \
        p0 += dppf<kXor1>(p0); p1 += dppf<kXor1>(p1);                         \
        p2 += dppf<kXor1>(p2); p3 += dppf<kXor1>(p3);                         \
        /* select own pair-gate (xor2 partner has same s&1 -> gate-uniform) */\
        float X = (s & 1) ? p1 : p0;                                          \
        float Y = (s & 1) ? p3 : p2;                                          \
        X += dppf<kXor2>(X); Y += dppf<kXor2>(Y);                             \
        const float z = ((s & 2) ? Y : X) + zcur;                             \
        /* one activation per lane (own gate) */                              \
        const float e = exp2_f(z * aScale);                                   \
        const float r = fast_rcp(1.0f + e);                                   \
        const float a = fmaf(r, aMul, aAdd);                                  \
        /* quad broadcasts: gate q lives in lane q of the quad */             \
        const float ai = dppf<kBc0>(a);                                       \
        const float af = dppf<kBc1>(a);                                       \
        const float ag = dppf<kBc2>(a);                                       \
        const float ao = dppf<kBc3>(a);                                       \
        const float cn = fmaf(af, c, ai * ag);                                \
        const float hn = ao * tanh_f(cn);                                     \
        if (mskc) { c = cn; hreg = hn; }   /* uniform branch */               \
        if (s == 0) s_hh[WP][u] = (_Float16)hreg;                             \
        __syncthreads();                                                      \
        zcur = znext; mskc = mskn;                                            \
        stokA = __builtin_amdgcn_readfirstlane(vtokB);                        \
    }

    for (int t = 0; t < kT; t += 2) {
        STEP(0, 1, t)
        STEP(1, 0, t + 1)
    }
#undef STEP
#undef DOTG

    // ---- epilogue: owner lanes publish exact f32 h, then reduce ----
    if (s == 0) s_act[u] = hreg;          // full-precision final h
    __syncthreads();
    if (tid < kU) {
        float v = s_act[tid] * Wd[tid] + hb_val * Wd[kU + tid];
#pragma unroll
        for (int off = 32; off > 0; off >>= 1) v += __shfl_down(v, off, 64);
        if (tid == 0) out[b] = v + bd[0];
    }
}

extern "C" void kernel_launch(void* const* d_in, const int* in_sizes, int n_in,
                              void* d_out, int out_size, void* d_ws, size_t ws_size,
                              hipStream_t stream) {
    const int*   tokens = (const int*)d_in[0];
    const float* emb    = (const float*)d_in[1];
    const float* Wk_f   = (const float*)d_in[2];
    const float* Wr_f   = (const float*)d_in[3];
    const float* b_f    = (const float*)d_in[4];
    const float* Wk_b   = (const float*)d_in[5];
    // d_in[6] = Wr_b: unused (backward runs one step from h0=0)
    const float* b_b    = (const float*)d_in[7];
    const float* Wd     = (const float*)d_in[8];
    const float* bd     = (const float*)d_in[9];
    float* out = (float*)d_out;

    bilstm_last_kernel<<<kB, 256, 0, stream>>>(
        tokens, emb, Wk_f, Wr_f, b_f, Wk_b, b_b, Wd, bd, out);
}